// Round 5
// baseline (726.185 us; speedup 1.0000x reference)
//
#include <hip/hip_runtime.h>
#include <hip/hip_bf16.h>
#include <math.h>

#define F_IN 200
#define HDIM 64
#define NPG  400
#define EPG  6400
#define KSEL 200   // NPG/2

// ---------------- pack [K,64]|[K,64] -> [K,128] ----------------
__global__ void pack_w(const float* __restrict__ Wl, const float* __restrict__ Wr,
                       float* __restrict__ Wc, int K) {
    int i = blockIdx.x * blockDim.x + threadIdx.x;
    if (i >= K * 128) return;
    int k = i >> 7, c = i & 127;
    Wc[i] = (c < 64) ? Wl[k * 64 + c] : Wr[k * 64 + (c - 64)];
}

// Thread tile mapping (256 threads, 128x128 output tile):
// c0 = (tid&15)*4, r0 = (tid>>4)*4; thread owns rows {r0..r0+3, +64}, cols {c0..c0+3, +64}.

// ---------------- GEMM K=200: O[N,128] = X[N,200] @ W[200,128] ----------------
// BK=40, 5 chunks, single-buffered LDS, 1 stall per chunk amortized over 5120 FMA-cyc.
__global__ __launch_bounds__(256) void gemm_k200(const float* __restrict__ X,
                                                 const float* __restrict__ W,
                                                 float* __restrict__ O) {
    __shared__ float Xs[128 * 44];     // stride 44 pad (bank spread), 22.5 KB
    __shared__ float Ws[40 * 128];     // 20 KB
    const int tid = threadIdx.x;
    const size_t rowbase = (size_t)blockIdx.x * 128;
    const int c0 = (tid & 15) * 4;
    const int r0 = (tid >> 4) * 4;

    float acc[2][2][4][4];
#pragma unroll
    for (int a = 0; a < 2; a++)
#pragma unroll
        for (int b = 0; b < 2; b++)
#pragma unroll
            for (int i = 0; i < 4; i++)
#pragma unroll
                for (int j = 0; j < 4; j++) acc[a][b][i][j] = 0.f;

    for (int c = 0; c < 5; c++) {
        if (c) __syncthreads();
        // stage X chunk: 128 rows x 40 k = 1280 float4, 5 per thread
#pragma unroll
        for (int t = 0; t < 5; t++) {
            int idx = tid + t * 256;
            int row = idx / 10, cc = (idx - row * 10) * 4;
            float4 v = *(const float4*)&X[(rowbase + row) * 200 + c * 40 + cc];
            *(float4*)&Xs[row * 44 + cc] = v;
        }
        // stage W chunk: 40 k x 128 = 1280 float4
#pragma unroll
        for (int t = 0; t < 5; t++) {
            int idx = tid + t * 256;
            int row = idx >> 5, cc = (idx & 31) * 4;
            *(float4*)&Ws[row * 128 + cc] = *(const float4*)&W[(size_t)(c * 40 + row) * 128 + cc];
        }
        __syncthreads();
#pragma unroll
        for (int k4 = 0; k4 < 40; k4 += 4) {
            float4 xr[8];
#pragma unroll
            for (int i = 0; i < 4; i++) {
                xr[i]     = *(const float4*)&Xs[(r0 + i) * 44 + k4];
                xr[4 + i] = *(const float4*)&Xs[(r0 + 64 + i) * 44 + k4];
            }
#pragma unroll
            for (int kk = 0; kk < 4; kk++) {
                float4 wa = *(const float4*)&Ws[(k4 + kk) * 128 + c0];
                float4 wb = *(const float4*)&Ws[(k4 + kk) * 128 + c0 + 64];
                const float ws0[4] = {wa.x, wa.y, wa.z, wa.w};
                const float ws1[4] = {wb.x, wb.y, wb.z, wb.w};
#pragma unroll
                for (int i = 0; i < 4; i++) {
                    float x0 = (kk == 0) ? xr[i].x : (kk == 1) ? xr[i].y : (kk == 2) ? xr[i].z : xr[i].w;
                    float x1 = (kk == 0) ? xr[4+i].x : (kk == 1) ? xr[4+i].y : (kk == 2) ? xr[4+i].z : xr[4+i].w;
#pragma unroll
                    for (int j = 0; j < 4; j++) {
                        acc[0][0][i][j] += x0 * ws0[j];
                        acc[0][1][i][j] += x0 * ws1[j];
                        acc[1][0][i][j] += x1 * ws0[j];
                        acc[1][1][i][j] += x1 * ws1[j];
                    }
                }
            }
        }
    }

#pragma unroll
    for (int a = 0; a < 2; a++)
#pragma unroll
        for (int i = 0; i < 4; i++) {
            size_t row = rowbase + r0 + a * 64 + i;
#pragma unroll
            for (int b = 0; b < 2; b++) {
                float4 v = make_float4(acc[a][b][i][0], acc[a][b][i][1],
                                       acc[a][b][i][2], acc[a][b][i][3]);
                *(float4*)&O[row * 128 + c0 + b * 64] = v;
            }
        }
}

// ---------------- GEMM K=64: O[N,128] = X[N,64] @ W[64,128] ----------------
// Whole X-tile (128x64) + whole W staged once: single stall, contiguous reads.
__global__ __launch_bounds__(256) void gemm_k64(const float* __restrict__ X,
                                                const float* __restrict__ W,
                                                float* __restrict__ O) {
    __shared__ float Xs[128 * 68];     // stride 68 pad, 34.8 KB
    __shared__ float Ws[64 * 128];     // 32 KB
    const int tid = threadIdx.x;
    const size_t rowbase = (size_t)blockIdx.x * 128;
    const int c0 = (tid & 15) * 4;
    const int r0 = (tid >> 4) * 4;

    // stage X: 128x64 = 2048 float4, 8 per thread (fully coalesced 256B rows)
#pragma unroll
    for (int t = 0; t < 8; t++) {
        int idx = tid + t * 256;
        int row = idx >> 4, cc = (idx & 15) * 4;
        float4 v = *(const float4*)&X[((size_t)(rowbase + row)) * 64 + cc];
        *(float4*)&Xs[row * 68 + cc] = v;
    }
    // stage W: 64x128 = 2048 float4
#pragma unroll
    for (int t = 0; t < 8; t++) {
        int idx = tid + t * 256;
        int row = idx >> 5, cc = (idx & 31) * 4;
        *(float4*)&Ws[row * 128 + cc] = *(const float4*)&W[(size_t)row * 128 + cc];
    }
    __syncthreads();

    float acc[2][2][4][4];
#pragma unroll
    for (int a = 0; a < 2; a++)
#pragma unroll
        for (int b = 0; b < 2; b++)
#pragma unroll
            for (int i = 0; i < 4; i++)
#pragma unroll
                for (int j = 0; j < 4; j++) acc[a][b][i][j] = 0.f;

#pragma unroll
    for (int k4 = 0; k4 < 64; k4 += 4) {
        float4 xr[8];
#pragma unroll
        for (int i = 0; i < 4; i++) {
            xr[i]     = *(const float4*)&Xs[(r0 + i) * 68 + k4];
            xr[4 + i] = *(const float4*)&Xs[(r0 + 64 + i) * 68 + k4];
        }
#pragma unroll
        for (int kk = 0; kk < 4; kk++) {
            float4 wa = *(const float4*)&Ws[(k4 + kk) * 128 + c0];
            float4 wb = *(const float4*)&Ws[(k4 + kk) * 128 + c0 + 64];
            const float ws0[4] = {wa.x, wa.y, wa.z, wa.w};
            const float ws1[4] = {wb.x, wb.y, wb.z, wb.w};
#pragma unroll
            for (int i = 0; i < 4; i++) {
                float x0 = (kk == 0) ? xr[i].x : (kk == 1) ? xr[i].y : (kk == 2) ? xr[i].z : xr[i].w;
                float x1 = (kk == 0) ? xr[4+i].x : (kk == 1) ? xr[4+i].y : (kk == 2) ? xr[4+i].z : xr[4+i].w;
#pragma unroll
                for (int j = 0; j < 4; j++) {
                    acc[0][0][i][j] += x0 * ws0[j];
                    acc[0][1][i][j] += x0 * ws1[j];
                    acc[1][0][i][j] += x1 * ws0[j];
                    acc[1][1][i][j] += x1 * ws1[j];
                }
            }
        }
    }

#pragma unroll
    for (int a = 0; a < 2; a++)
#pragma unroll
        for (int i = 0; i < 4; i++) {
            size_t row = rowbase + r0 + a * 64 + i;
#pragma unroll
            for (int b = 0; b < 2; b++) {
                float4 v = make_float4(acc[a][b][i][0], acc[a][b][i][1],
                                       acc[a][b][i][2], acc[a][b][i][3]);
                *(float4*)&O[row * 128 + c0 + b * 64] = v;
            }
        }
}

// ---------------- CSR build: one block per graph ----------------
__global__ __launch_bounds__(256) void csr_build(
    const int* __restrict__ esrc, const int* __restrict__ edst,
    int* __restrict__ csr_src, int* __restrict__ rowptr,
    int* __restrict__ degs, float* __restrict__ invdeg)
{
    __shared__ int cnt[NPG];
    __shared__ int off[NPG];
    __shared__ int cur[NPG];
    const int g = blockIdx.x, tid = threadIdx.x;
    const int ebase = g * EPG, nodebase = g * NPG;
    for (int i = tid; i < NPG; i += 256) cnt[i] = 0;
    __syncthreads();
    for (int e = tid; e < EPG; e += 256)
        atomicAdd(&cnt[edst[ebase + e] - nodebase], 1);
    __syncthreads();
    if (tid == 0) {
        int run = 0;
        for (int i = 0; i < NPG; i++) { off[i] = run; run += cnt[i]; }
    }
    __syncthreads();
    for (int i = tid; i < NPG; i += 256) {
        cur[i] = off[i];
        rowptr[nodebase + i] = off[i];
        degs[nodebase + i] = cnt[i];
        invdeg[nodebase + i] = 1.f / fmaxf((float)cnt[i], 1.f);
    }
    __syncthreads();
    for (int e = tid; e < EPG; e += 256) {
        int ld = edst[ebase + e] - nodebase;
        int p = atomicAdd(&cur[ld], 1);
        csr_src[ebase + p] = esrc[ebase + e] - nodebase;  // local src
    }
}

// ---------------- fused per-graph aggregate+combine (LDS-staged) ----------------
__global__ __launch_bounds__(1024) void agg_lds(
    const float* __restrict__ A,
    const int* __restrict__ csr_src, const int* __restrict__ rowptr,
    const int* __restrict__ degs, const float* __restrict__ invdeg,
    const float* __restrict__ bias,
    const float* __restrict__ resid,
    float* __restrict__ Xout)
{
    __shared__ float y[NPG * 64];     // 102400 B
    __shared__ int   csr_l[EPG];      // 25600 B
    const int g = blockIdx.x, tid = threadIdx.x;
    const int ebase = g * EPG, nodebase = g * NPG;

    for (int idx = tid; idx < NPG * 16; idx += 1024) {
        int node = idx >> 4, c4 = (idx & 15) * 4;
        *(float4*)&y[node * 64 + c4] =
            *(const float4*)&A[(size_t)(nodebase + node) * 128 + c4];
    }
    for (int e = tid; e < EPG; e += 1024) csr_l[e] = csr_src[ebase + e];
    __syncthreads();

    const int wave = tid >> 6, lane = tid & 63;
    for (int node = wave; node < NPG; node += 16) {
        const int start = rowptr[nodebase + node];
        const int dg = degs[nodebase + node];
        float acc = 0.f;
        int j = 0;
        for (; j + 4 <= dg; j += 4) {
            int s0 = csr_l[start + j];
            int s1 = csr_l[start + j + 1];
            int s2 = csr_l[start + j + 2];
            int s3 = csr_l[start + j + 3];
            acc += y[s0 * 64 + lane] + y[s1 * 64 + lane]
                 + y[s2 * 64 + lane] + y[s3 * 64 + lane];
        }
        for (; j < dg; j++) acc += y[csr_l[start + j] * 64 + lane];

        float v = acc * invdeg[nodebase + node] + bias[lane]
                + A[(size_t)(nodebase + node) * 128 + 64 + lane];
        v = fmaxf(v, 0.f);
        if (resid) v += resid[(size_t)(nodebase + node) * 64 + lane];
        Xout[(size_t)(nodebase + node) * 64 + lane] = v;
    }
}

// ---------------- per-graph score + top-k + pool + classifier ----------------
__global__ __launch_bounds__(256) void score_pool(
    const float* __restrict__ X3,
    const int* __restrict__ esrc, const int* __restrict__ edst,
    const float* __restrict__ Wpr, const float* __restrict__ bpr,
    const float* __restrict__ Wpo,
    const float* __restrict__ Wlin, const float* __restrict__ blin,
    float* __restrict__ out)
{
    __shared__ float t0[NPG], s[NPG], w[NPG];
    __shared__ float wpr[64], wpo[64];
    __shared__ float pp[4 * 64];
    __shared__ float pooled[64];
    __shared__ float lg[2];
    const int g = blockIdx.x, tid = threadIdx.x;
    if (tid < 64) { wpr[tid] = Wpr[tid]; wpo[tid] = Wpo[tid]; }
    __syncthreads();

    const int nodebase = g * NPG;
    for (int i = tid; i < NPG; i += 256) {
        const float* xr = &X3[(size_t)(nodebase + i) * 64];
        float a0 = 0.f, a1 = 0.f;
        for (int d = 0; d < 64; d++) { float x = xr[d]; a0 += x * wpr[d]; a1 += x * wpo[d]; }
        t0[i] = a0;
        s[i] = bpr[0] + a1;
    }
    __syncthreads();
    const int ebase = g * EPG;
    for (int e = tid; e < EPG; e += 256) {
        int ls = esrc[ebase + e] - nodebase;
        int ld = edst[ebase + e] - nodebase;
        atomicAdd(&s[ld], t0[ls]);
    }
    __syncthreads();
    for (int i = tid; i < NPG; i += 256) {
        float si = s[i];
        int cnt = 0;
        for (int j = 0; j < NPG; j++) {
            float sj = s[j];
            cnt += (sj > si) || (sj == si && j < i);
        }
        w[i] = (cnt < KSEL) ? tanhf(si) * (1.f / KSEL) : 0.f;
    }
    __syncthreads();
    const int d = tid & 63, part = tid >> 6;
    float acc = 0.f;
    for (int i = part * 100; i < part * 100 + 100; i++)
        acc += w[i] * X3[(size_t)(nodebase + i) * 64 + d];
    pp[part * 64 + d] = acc;
    __syncthreads();
    if (tid < 64) pooled[tid] = pp[tid] + pp[64 + tid] + pp[128 + tid] + pp[192 + tid];
    __syncthreads();
    if (tid < 2) {
        float l = blin[tid];
        for (int dd = 0; dd < 64; dd++) l += pooled[dd] * Wlin[dd * 2 + tid];
        lg[tid] = l;
    }
    __syncthreads();
    if (tid < 2) {
        float m = fmaxf(lg[0], lg[1]);
        float lse = m + logf(expf(lg[0] - m) + expf(lg[1] - m));
        out[g * 2 + tid] = lg[tid] - lse;
    }
}

extern "C" void kernel_launch(void* const* d_in, const int* in_sizes, int n_in,
                              void* d_out, int out_size, void* d_ws, size_t ws_size,
                              hipStream_t stream) {
    const float* x    = (const float*)d_in[0];
    const int*   eidx = (const int*)d_in[1];
    const float* W1l  = (const float*)d_in[3];
    const float* W1r  = (const float*)d_in[4];
    const float* b1   = (const float*)d_in[5];
    const float* W2l  = (const float*)d_in[6];
    const float* W2r  = (const float*)d_in[7];
    const float* b2   = (const float*)d_in[8];
    const float* W3l  = (const float*)d_in[9];
    const float* W3r  = (const float*)d_in[10];
    const float* b3   = (const float*)d_in[11];
    const float* Wpr  = (const float*)d_in[12];
    const float* bpr  = (const float*)d_in[13];
    const float* Wpo  = (const float*)d_in[14];
    const float* Wlin = (const float*)d_in[15];
    const float* blin = (const float*)d_in[16];

    const int N = in_sizes[0] / F_IN;       // 204800
    const int E = in_sizes[1] / 2;          // 3276800
    const int B = N / NPG;                  // 512
    const int* esrc = eidx;
    const int* edst = eidx + E;

    float* ws = (float*)d_ws;
    float* A      = ws;                                  // [N,128] yz buffer
    float* P0     = A + (size_t)N * 128;                 // [N,64] compact acts
    float* P1     = P0 + (size_t)N * 64;                 // [N,64] compact acts
    float* invdeg = P1 + (size_t)N * 64;                 // [N]
    float* Wc1    = invdeg + N;                          // [200,128]
    float* Wc2    = Wc1 + 200 * 128;                     // [64,128]
    float* Wc3    = Wc2 + 64 * 128;                      // [64,128]
    int*   csr    = (int*)(Wc3 + 64 * 128);              // [E] local src by dst
    int*   rowptr = csr + E;                             // [N] local offsets
    int*   degs   = rowptr + N;                          // [N]

    pack_w<<<(200 * 128 + 255) / 256, 256, 0, stream>>>(W1l, W1r, Wc1, 200);
    pack_w<<<(64 * 128 + 255) / 256, 256, 0, stream>>>(W2l, W2r, Wc2, 64);
    pack_w<<<(64 * 128 + 255) / 256, 256, 0, stream>>>(W3l, W3r, Wc3, 64);

    // CSR once (shared by all 3 layers)
    csr_build<<<B, 256, 0, stream>>>(esrc, edst, csr, rowptr, degs, invdeg);

    // layer 1: yz = x @ [W1l|W1r]; x1 -> P0
    gemm_k200<<<N / 128, 256, 0, stream>>>(x, Wc1, A);
    agg_lds<<<B, 1024, 0, stream>>>(A, csr, rowptr, degs, invdeg, b1, nullptr, P0);

    // layer 2: yz = x1 @ [W2l|W2r]; x2 = relu(...)+x1 -> P1
    gemm_k64<<<N / 128, 256, 0, stream>>>(P0, Wc2, A);
    agg_lds<<<B, 1024, 0, stream>>>(A, csr, rowptr, degs, invdeg, b2, P0, P1);

    // layer 3: yz = x2 @ [W3l|W3r]; x3 = relu(...)+x2 -> P0 (x1 dead)
    gemm_k64<<<N / 128, 256, 0, stream>>>(P1, Wc3, A);
    agg_lds<<<B, 1024, 0, stream>>>(A, csr, rowptr, degs, invdeg, b3, P1, P0);

    // score + top-k + pool + classifier
    score_pool<<<B, 256, 0, stream>>>(P0, esrc, edst, Wpr, bpr, Wpo, Wlin, blin,
                                      (float*)d_out);
}

// Round 6
// 507.853 us; speedup vs baseline: 1.4299x; 1.4299x over previous
//
#include <hip/hip_runtime.h>
#include <hip/hip_bf16.h>
#include <math.h>

#define F_IN 200
#define HDIM 64
#define NPG  400
#define EPG  6400
#define KSEL 200   // NPG/2

typedef __attribute__((ext_vector_type(4))) float f32x4;
typedef __attribute__((ext_vector_type(8))) short s16x8;

// RNE float -> bf16 bits
__device__ __forceinline__ unsigned int bf16_rne(float x) {
    unsigned int b = __float_as_uint(x);
    return (b + 0x7FFFu + ((b >> 16) & 1u)) >> 16;
}

// split x into bf16 hi + bf16 lo (x ~= hi + lo, rel err ~2^-17)
__device__ __forceinline__ void split8(f32x4 v0, f32x4 v1, s16x8& h, s16x8& l) {
    float x[8] = {v0.x, v0.y, v0.z, v0.w, v1.x, v1.y, v1.z, v1.w};
#pragma unroll
    for (int j = 0; j < 8; j++) {
        unsigned int hb = bf16_rne(x[j]);
        float hf = __uint_as_float(hb << 16);
        float r = x[j] - hf;
        unsigned int lb = bf16_rne(r);
        h[j] = (short)hb;
        l[j] = (short)lb;
    }
}

// ---------------- pack W ([K,64]|[K,64] fp32) -> fragment-ordered bf16 pairs --
// WF layout: frag f = (kc*8+nf)*2+p  (p=0 hi, p=1 lo); short index f*512+lane*8+j
// fragment element: k = kc*32 + (lane>>4)*8 + j ; n = nf*16 + (lane&15)
__global__ void pack_wf(const float* __restrict__ Wl, const float* __restrict__ Wr,
                        short* __restrict__ WF, int K, int KC) {
    int idx = blockIdx.x * blockDim.x + threadIdx.x;
    if (idx >= KC * 4096) return;
    int j    = idx & 7;
    int lane = (idx >> 3) & 63;
    int nf   = (idx >> 9) & 7;
    int kc   = idx >> 12;
    int k = kc * 32 + (lane >> 4) * 8 + j;
    int n = nf * 16 + (lane & 15);
    float v = 0.f;
    if (k < K) v = (n < 64) ? Wl[k * 64 + n] : Wr[k * 64 + (n - 64)];
    unsigned int hb = bf16_rne(v);
    float hf = __uint_as_float(hb << 16);
    unsigned int lb = bf16_rne(v - hf);
    WF[(size_t)((kc * 8 + nf) * 2 + 0) * 512 + lane * 8 + j] = (short)hb;
    WF[(size_t)((kc * 8 + nf) * 2 + 1) * 512 + lane * 8 + j] = (short)lb;
}

// ---------------- MFMA GEMM: O[N,128] = X[N,K] @ W[K,128] ----------------
// 128x128 tile, 256 threads (4 waves), wave handles m-frags {2w,2w+1} x 8 n-frags.
// X staged fp32 in fragment-ordered LDS; split to bf16 pairs in-register.
// W read as fragment-ordered bf16 pairs from global (L2-resident).
// 3 MFMAs per fragment pair: xh*wh + al*wh + ah*wl (split product).
template <int K, int LDX, int KC>
__global__ __launch_bounds__(256) void gemm_mfma(const float* __restrict__ X,
                                                 const short* __restrict__ WF,
                                                 float* __restrict__ O) {
    __shared__ f32x4 XsV[16 * 64];   // [mf*2+h][lane] : 1024 f32x4 = 16 KB
    const int tid  = threadIdx.x;
    const int lane = tid & 63;
    const int wave = tid >> 6;
    const size_t rowbase = (size_t)blockIdx.x * 128;
    const s16x8* WFv = (const s16x8*)WF;

    f32x4 acc[2][8];
#pragma unroll
    for (int m = 0; m < 2; m++)
#pragma unroll
        for (int nf = 0; nf < 8; nf++) acc[m][nf] = (f32x4){0.f, 0.f, 0.f, 0.f};

    f32x4 pre[4];
#define LOAD_CHUNK(kc_) {                                                        \
    _Pragma("unroll")                                                            \
    for (int i = 0; i < 4; i++) {                                                \
        int idx = tid + i * 256;                                                 \
        int row = idx & 127, kk = (idx >> 7) * 4;                                \
        if (K - (kc_) * 32 - kk >= 4)                                            \
            pre[i] = *(const f32x4*)&X[(rowbase + row) * (size_t)LDX + (kc_) * 32 + kk]; \
        else pre[i] = (f32x4){0.f, 0.f, 0.f, 0.f};                               \
    } }

    LOAD_CHUNK(0);
    for (int kc = 0; kc < KC; kc++) {
        if (kc) __syncthreads();
        // write staged chunk into fragment-ordered LDS
#pragma unroll
        for (int i = 0; i < 4; i++) {
            int idx = tid + i * 256;
            int row = idx & 127, kk = (idx >> 7) * 4;
            int mf = row >> 4, h = (kk >> 2) & 1, ls = (row & 15) + 16 * (kk >> 3);
            XsV[(mf * 2 + h) * 64 + ls] = pre[i];
        }
        if (kc + 1 < KC) LOAD_CHUNK(kc + 1);
        __syncthreads();

        // A fragments for this wave's two m-frags
        s16x8 ah[2], al[2];
#pragma unroll
        for (int m = 0; m < 2; m++) {
            int mf = wave * 2 + m;
            f32x4 v0 = XsV[(mf * 2 + 0) * 64 + lane];
            f32x4 v1 = XsV[(mf * 2 + 1) * 64 + lane];
            split8(v0, v1, ah[m], al[m]);
        }
#pragma unroll
        for (int nf = 0; nf < 8; nf++) {
            const s16x8* bp = WFv + (size_t)(kc * 8 + nf) * 128 + lane;
            s16x8 wh = bp[0];
            s16x8 wl = bp[64];
#pragma unroll
            for (int m = 0; m < 2; m++) {
                acc[m][nf] = __builtin_amdgcn_mfma_f32_16x16x32_bf16(ah[m], wh, acc[m][nf], 0, 0, 0);
                acc[m][nf] = __builtin_amdgcn_mfma_f32_16x16x32_bf16(al[m], wh, acc[m][nf], 0, 0, 0);
                acc[m][nf] = __builtin_amdgcn_mfma_f32_16x16x32_bf16(ah[m], wl, acc[m][nf], 0, 0, 0);
            }
        }
    }
#undef LOAD_CHUNK

    // store: D reg r at lane l -> row (lane>>4)*4+r, col lane&15 of the 16x16 frag
#pragma unroll
    for (int m = 0; m < 2; m++) {
        size_t row0 = rowbase + (wave * 2 + m) * 16 + (lane >> 4) * 4;
        int col0 = lane & 15;
#pragma unroll
        for (int nf = 0; nf < 8; nf++)
#pragma unroll
            for (int r = 0; r < 4; r++)
                O[(row0 + r) * 128 + nf * 16 + col0] = acc[m][nf][r];
    }
}

// ---------------- CSR build: one block per graph ----------------
__global__ __launch_bounds__(256) void csr_build(
    const int* __restrict__ esrc, const int* __restrict__ edst,
    int* __restrict__ csr_src, int* __restrict__ rowptr,
    int* __restrict__ degs, float* __restrict__ invdeg)
{
    __shared__ int cnt[NPG];
    __shared__ int off[NPG];
    __shared__ int cur[NPG];
    const int g = blockIdx.x, tid = threadIdx.x;
    const int ebase = g * EPG, nodebase = g * NPG;
    for (int i = tid; i < NPG; i += 256) cnt[i] = 0;
    __syncthreads();
    for (int e = tid; e < EPG; e += 256)
        atomicAdd(&cnt[edst[ebase + e] - nodebase], 1);
    __syncthreads();
    if (tid == 0) {
        int run = 0;
        for (int i = 0; i < NPG; i++) { off[i] = run; run += cnt[i]; }
    }
    __syncthreads();
    for (int i = tid; i < NPG; i += 256) {
        cur[i] = off[i];
        rowptr[nodebase + i] = off[i];
        degs[nodebase + i] = cnt[i];
        invdeg[nodebase + i] = 1.f / fmaxf((float)cnt[i], 1.f);
    }
    __syncthreads();
    for (int e = tid; e < EPG; e += 256) {
        int ld = edst[ebase + e] - nodebase;
        int p = atomicAdd(&cur[ld], 1);
        csr_src[ebase + p] = esrc[ebase + e] - nodebase;  // local src
    }
}

// ---------------- fused per-graph aggregate+combine (LDS-staged) ----------------
__global__ __launch_bounds__(1024) void agg_lds(
    const float* __restrict__ A,
    const int* __restrict__ csr_src, const int* __restrict__ rowptr,
    const int* __restrict__ degs, const float* __restrict__ invdeg,
    const float* __restrict__ bias,
    const float* __restrict__ resid,
    float* __restrict__ Xout)
{
    __shared__ float y[NPG * 64];     // 102400 B
    __shared__ int   csr_l[EPG];      // 25600 B
    const int g = blockIdx.x, tid = threadIdx.x;
    const int ebase = g * EPG, nodebase = g * NPG;

    for (int idx = tid; idx < NPG * 16; idx += 1024) {
        int node = idx >> 4, c4 = (idx & 15) * 4;
        *(float4*)&y[node * 64 + c4] =
            *(const float4*)&A[(size_t)(nodebase + node) * 128 + c4];
    }
    for (int e = tid; e < EPG; e += 1024) csr_l[e] = csr_src[ebase + e];
    __syncthreads();

    const int wave = tid >> 6, lane = tid & 63;
    for (int node = wave; node < NPG; node += 16) {
        const int start = rowptr[nodebase + node];
        const int dg = degs[nodebase + node];
        float acc = 0.f;
        int j = 0;
        for (; j + 4 <= dg; j += 4) {
            int s0 = csr_l[start + j];
            int s1 = csr_l[start + j + 1];
            int s2 = csr_l[start + j + 2];
            int s3 = csr_l[start + j + 3];
            acc += y[s0 * 64 + lane] + y[s1 * 64 + lane]
                 + y[s2 * 64 + lane] + y[s3 * 64 + lane];
        }
        for (; j < dg; j++) acc += y[csr_l[start + j] * 64 + lane];

        float v = acc * invdeg[nodebase + node] + bias[lane]
                + A[(size_t)(nodebase + node) * 128 + 64 + lane];
        v = fmaxf(v, 0.f);
        if (resid) v += resid[(size_t)(nodebase + node) * 64 + lane];
        Xout[(size_t)(nodebase + node) * 64 + lane] = v;
    }
}

// ---------------- per-graph score + top-k + pool + classifier ----------------
__global__ __launch_bounds__(256) void score_pool(
    const float* __restrict__ X3,
    const int* __restrict__ esrc, const int* __restrict__ edst,
    const float* __restrict__ Wpr, const float* __restrict__ bpr,
    const float* __restrict__ Wpo,
    const float* __restrict__ Wlin, const float* __restrict__ blin,
    float* __restrict__ out)
{
    __shared__ float t0[NPG], s[NPG], w[NPG];
    __shared__ float wpr[64], wpo[64];
    __shared__ float pp[4 * 64];
    __shared__ float pooled[64];
    __shared__ float lg[2];
    const int g = blockIdx.x, tid = threadIdx.x;
    if (tid < 64) { wpr[tid] = Wpr[tid]; wpo[tid] = Wpo[tid]; }
    __syncthreads();

    const int nodebase = g * NPG;
    for (int i = tid; i < NPG; i += 256) {
        const float* xr = &X3[(size_t)(nodebase + i) * 64];
        float a0 = 0.f, a1 = 0.f;
        for (int d = 0; d < 64; d++) { float x = xr[d]; a0 += x * wpr[d]; a1 += x * wpo[d]; }
        t0[i] = a0;
        s[i] = bpr[0] + a1;
    }
    __syncthreads();
    const int ebase = g * EPG;
    for (int e = tid; e < EPG; e += 256) {
        int ls = esrc[ebase + e] - nodebase;
        int ld = edst[ebase + e] - nodebase;
        atomicAdd(&s[ld], t0[ls]);
    }
    __syncthreads();
    for (int i = tid; i < NPG; i += 256) {
        float si = s[i];
        int cnt = 0;
        for (int j = 0; j < NPG; j++) {
            float sj = s[j];
            cnt += (sj > si) || (sj == si && j < i);
        }
        w[i] = (cnt < KSEL) ? tanhf(si) * (1.f / KSEL) : 0.f;
    }
    __syncthreads();
    const int d = tid & 63, part = tid >> 6;
    float acc = 0.f;
    for (int i = part * 100; i < part * 100 + 100; i++)
        acc += w[i] * X3[(size_t)(nodebase + i) * 64 + d];
    pp[part * 64 + d] = acc;
    __syncthreads();
    if (tid < 64) pooled[tid] = pp[tid] + pp[64 + tid] + pp[128 + tid] + pp[192 + tid];
    __syncthreads();
    if (tid < 2) {
        float l = blin[tid];
        for (int dd = 0; dd < 64; dd++) l += pooled[dd] * Wlin[dd * 2 + tid];
        lg[tid] = l;
    }
    __syncthreads();
    if (tid < 2) {
        float m = fmaxf(lg[0], lg[1]);
        float lse = m + logf(expf(lg[0] - m) + expf(lg[1] - m));
        out[g * 2 + tid] = lg[tid] - lse;
    }
}

extern "C" void kernel_launch(void* const* d_in, const int* in_sizes, int n_in,
                              void* d_out, int out_size, void* d_ws, size_t ws_size,
                              hipStream_t stream) {
    const float* x    = (const float*)d_in[0];
    const int*   eidx = (const int*)d_in[1];
    const float* W1l  = (const float*)d_in[3];
    const float* W1r  = (const float*)d_in[4];
    const float* b1   = (const float*)d_in[5];
    const float* W2l  = (const float*)d_in[6];
    const float* W2r  = (const float*)d_in[7];
    const float* b2   = (const float*)d_in[8];
    const float* W3l  = (const float*)d_in[9];
    const float* W3r  = (const float*)d_in[10];
    const float* b3   = (const float*)d_in[11];
    const float* Wpr  = (const float*)d_in[12];
    const float* bpr  = (const float*)d_in[13];
    const float* Wpo  = (const float*)d_in[14];
    const float* Wlin = (const float*)d_in[15];
    const float* blin = (const float*)d_in[16];

    const int N = in_sizes[0] / F_IN;       // 204800
    const int E = in_sizes[1] / 2;          // 3276800
    const int B = N / NPG;                  // 512
    const int* esrc = eidx;
    const int* edst = eidx + E;

    float* ws = (float*)d_ws;
    float* A      = ws;                                  // [N,128] yz buffer
    float* P0     = A + (size_t)N * 128;                 // [N,64] compact acts
    float* P1     = P0 + (size_t)N * 64;                 // [N,64] compact acts
    float* invdeg = P1 + (size_t)N * 64;                 // [N]
    short* WF1    = (short*)(invdeg + N);                // 7*8*2*512 = 57344 sh
    short* WF2    = WF1 + 57344;                         // 2*8*2*512 = 16384 sh
    short* WF3    = WF2 + 16384;
    int*   csr    = (int*)(WF3 + 16384);                 // [E] local src by dst
    int*   rowptr = csr + E;                             // [N] local offsets
    int*   degs   = rowptr + N;                          // [N]

    pack_wf<<<(7 * 4096 + 255) / 256, 256, 0, stream>>>(W1l, W1r, WF1, 200, 7);
    pack_wf<<<(2 * 4096 + 255) / 256, 256, 0, stream>>>(W2l, W2r, WF2, 64, 2);
    pack_wf<<<(2 * 4096 + 255) / 256, 256, 0, stream>>>(W3l, W3r, WF3, 64, 2);

    // CSR once (shared by all 3 layers)
    csr_build<<<B, 256, 0, stream>>>(esrc, edst, csr, rowptr, degs, invdeg);

    // layer 1: yz = x @ [W1l|W1r]; x1 -> P0
    gemm_mfma<200, 200, 7><<<N / 128, 256, 0, stream>>>(x, WF1, A);
    agg_lds<<<B, 1024, 0, stream>>>(A, csr, rowptr, degs, invdeg, b1, nullptr, P0);

    // layer 2: yz = x1 @ [W2l|W2r]; x2 = relu(...)+x1 -> P1
    gemm_mfma<64, 64, 2><<<N / 128, 256, 0, stream>>>(P0, WF2, A);
    agg_lds<<<B, 1024, 0, stream>>>(A, csr, rowptr, degs, invdeg, b2, P0, P1);

    // layer 3: yz = x2 @ [W3l|W3r]; x3 = relu(...)+x2 -> P0 (x1 dead)
    gemm_mfma<64, 64, 2><<<N / 128, 256, 0, stream>>>(P1, WF3, A);
    agg_lds<<<B, 1024, 0, stream>>>(A, csr, rowptr, degs, invdeg, b3, P1, P0);

    // score + top-k + pool + classifier
    score_pool<<<B, 256, 0, stream>>>(P0, esrc, edst, Wpr, bpr, Wpo, Wlin, blin,
                                      (float*)d_out);
}

// Round 7
// 492.024 us; speedup vs baseline: 1.4759x; 1.0322x over previous
//
#include <hip/hip_runtime.h>
#include <hip/hip_bf16.h>
#include <math.h>

#define F_IN 200
#define HDIM 64
#define NPG  400
#define EPG  6400
#define KSEL 200   // NPG/2

typedef __attribute__((ext_vector_type(4))) float f32x4;
typedef __attribute__((ext_vector_type(8))) short s16x8;

// RNE float -> bf16 bits
__device__ __forceinline__ unsigned int bf16_rne(float x) {
    unsigned int b = __float_as_uint(x);
    return (b + 0x7FFFu + ((b >> 16) & 1u)) >> 16;
}

// split x into bf16 hi + bf16 lo (x ~= hi + lo, rel err ~2^-17)
__device__ __forceinline__ void split8(f32x4 v0, f32x4 v1, s16x8& h, s16x8& l) {
    float x[8] = {v0.x, v0.y, v0.z, v0.w, v1.x, v1.y, v1.z, v1.w};
#pragma unroll
    for (int j = 0; j < 8; j++) {
        unsigned int hb = bf16_rne(x[j]);
        float hf = __uint_as_float(hb << 16);
        float r = x[j] - hf;
        unsigned int lb = bf16_rne(r);
        h[j] = (short)hb;
        l[j] = (short)lb;
    }
}

// ---------------- pack W ([K,64]|[K,64] fp32) -> fragment-ordered bf16 pairs --
// WF layout: frag f = (kc*8+nf)*2+p  (p=0 hi, p=1 lo); short index f*512+lane*8+j
// fragment element: k = kc*32 + (lane>>4)*8 + j ; n = nf*16 + (lane&15)
__global__ void pack_wf(const float* __restrict__ Wl, const float* __restrict__ Wr,
                        short* __restrict__ WF, int K, int KC) {
    int idx = blockIdx.x * blockDim.x + threadIdx.x;
    if (idx >= KC * 4096) return;
    int j    = idx & 7;
    int lane = (idx >> 3) & 63;
    int nf   = (idx >> 9) & 7;
    int kc   = idx >> 12;
    int k = kc * 32 + (lane >> 4) * 8 + j;
    int n = nf * 16 + (lane & 15);
    float v = 0.f;
    if (k < K) v = (n < 64) ? Wl[k * 64 + n] : Wr[k * 64 + (n - 64)];
    unsigned int hb = bf16_rne(v);
    float hf = __uint_as_float(hb << 16);
    unsigned int lb = bf16_rne(v - hf);
    WF[(size_t)((kc * 8 + nf) * 2 + 0) * 512 + lane * 8 + j] = (short)hb;
    WF[(size_t)((kc * 8 + nf) * 2 + 1) * 512 + lane * 8 + j] = (short)lb;
}

// ---------------- MFMA GEMM, wave-independent: O[N,128] = X[N,K] @ W[K,128] --
// Each wave owns a 32x128 output tile (2 m-frags x 8 n-frags), reads its A
// fragments directly from global (no LDS, no barriers), W from fragment-ordered
// global buffer (L2-resident). 3 MFMAs per fragment pair (split bf16 product).
template <int K, int LDX, int KC>
__global__ __launch_bounds__(256) void gemm_mfma(const float* __restrict__ X,
                                                 const short* __restrict__ WF,
                                                 float* __restrict__ O) {
    const int tid  = threadIdx.x;
    const int lane = tid & 63;
    const int wave = tid >> 6;
    const size_t rowbase = (size_t)(blockIdx.x * 4 + wave) * 32;
    const s16x8* WFv = (const s16x8*)WF;

    const int arow0 = (lane & 15);          // row within m-frag
    const int ak0   = (lane >> 4) * 8;      // k offset within 32-k chunk

    f32x4 acc[2][8];
#pragma unroll
    for (int m = 0; m < 2; m++)
#pragma unroll
        for (int nf = 0; nf < 8; nf++) acc[m][nf] = (f32x4){0.f, 0.f, 0.f, 0.f};

    for (int kc = 0; kc < KC; kc++) {
        // A fragment loads: per m-frag two f32x4 straight from global
        f32x4 av[2][2];
#pragma unroll
        for (int m = 0; m < 2; m++) {
            size_t row = rowbase + m * 16 + arow0;
#pragma unroll
            for (int h = 0; h < 2; h++) {
                int k0 = kc * 32 + ak0 + h * 4;
                if (k0 + 4 <= K)
                    av[m][h] = *(const f32x4*)&X[row * (size_t)LDX + k0];
                else
                    av[m][h] = (f32x4){0.f, 0.f, 0.f, 0.f};
            }
        }
        // W fragment loads for this chunk (16 x 16B, independent)
        s16x8 wh[8], wl[8];
#pragma unroll
        for (int nf = 0; nf < 8; nf++) {
            const s16x8* bp = WFv + (size_t)(kc * 8 + nf) * 128 + lane;
            wh[nf] = bp[0];
            wl[nf] = bp[64];
        }
        s16x8 ah[2], al[2];
#pragma unroll
        for (int m = 0; m < 2; m++) split8(av[m][0], av[m][1], ah[m], al[m]);
#pragma unroll
        for (int nf = 0; nf < 8; nf++) {
#pragma unroll
            for (int m = 0; m < 2; m++) {
                acc[m][nf] = __builtin_amdgcn_mfma_f32_16x16x32_bf16(ah[m], wh[nf], acc[m][nf], 0, 0, 0);
                acc[m][nf] = __builtin_amdgcn_mfma_f32_16x16x32_bf16(al[m], wh[nf], acc[m][nf], 0, 0, 0);
                acc[m][nf] = __builtin_amdgcn_mfma_f32_16x16x32_bf16(ah[m], wl[nf], acc[m][nf], 0, 0, 0);
            }
        }
    }

    // store: D reg r at lane l -> row (lane>>4)*4+r, col lane&15 of the 16x16 frag
#pragma unroll
    for (int m = 0; m < 2; m++) {
        size_t row0 = rowbase + m * 16 + (lane >> 4) * 4;
        int col0 = lane & 15;
#pragma unroll
        for (int nf = 0; nf < 8; nf++)
#pragma unroll
            for (int r = 0; r < 4; r++)
                O[(row0 + r) * 128 + nf * 16 + col0] = acc[m][nf][r];
    }
}

// ---------------- CSR build: one block per graph ----------------
__global__ __launch_bounds__(256) void csr_build(
    const int* __restrict__ esrc, const int* __restrict__ edst,
    int* __restrict__ csr_src, int* __restrict__ rowptr,
    int* __restrict__ degs, float* __restrict__ invdeg)
{
    __shared__ int cnt[NPG];
    __shared__ int off[NPG];
    __shared__ int cur[NPG];
    const int g = blockIdx.x, tid = threadIdx.x;
    const int ebase = g * EPG, nodebase = g * NPG;
    for (int i = tid; i < NPG; i += 256) cnt[i] = 0;
    __syncthreads();
    for (int e = tid; e < EPG; e += 256)
        atomicAdd(&cnt[edst[ebase + e] - nodebase], 1);
    __syncthreads();
    if (tid == 0) {
        int run = 0;
        for (int i = 0; i < NPG; i++) { off[i] = run; run += cnt[i]; }
    }
    __syncthreads();
    for (int i = tid; i < NPG; i += 256) {
        cur[i] = off[i];
        rowptr[nodebase + i] = off[i];
        degs[nodebase + i] = cnt[i];
        invdeg[nodebase + i] = 1.f / fmaxf((float)cnt[i], 1.f);
    }
    __syncthreads();
    for (int e = tid; e < EPG; e += 256) {
        int ld = edst[ebase + e] - nodebase;
        int p = atomicAdd(&cur[ld], 1);
        csr_src[ebase + p] = esrc[ebase + e] - nodebase;  // local src
    }
}

// ---------------- fused per-graph aggregate+combine (LDS-staged) ----------------
__global__ __launch_bounds__(1024) void agg_lds(
    const float* __restrict__ A,
    const int* __restrict__ csr_src, const int* __restrict__ rowptr,
    const int* __restrict__ degs, const float* __restrict__ invdeg,
    const float* __restrict__ bias,
    const float* __restrict__ resid,
    float* __restrict__ Xout)
{
    __shared__ float y[NPG * 64];     // 102400 B
    __shared__ int   csr_l[EPG];      // 25600 B
    const int g = blockIdx.x, tid = threadIdx.x;
    const int ebase = g * EPG, nodebase = g * NPG;

    for (int idx = tid; idx < NPG * 16; idx += 1024) {
        int node = idx >> 4, c4 = (idx & 15) * 4;
        *(float4*)&y[node * 64 + c4] =
            *(const float4*)&A[(size_t)(nodebase + node) * 128 + c4];
    }
    for (int e = tid; e < EPG; e += 1024) csr_l[e] = csr_src[ebase + e];
    __syncthreads();

    const int wave = tid >> 6, lane = tid & 63;
    for (int node = wave; node < NPG; node += 16) {
        const int start = rowptr[nodebase + node];
        const int dg = degs[nodebase + node];
        float acc = 0.f;
        int j = 0;
        for (; j + 4 <= dg; j += 4) {
            int s0 = csr_l[start + j];
            int s1 = csr_l[start + j + 1];
            int s2 = csr_l[start + j + 2];
            int s3 = csr_l[start + j + 3];
            acc += y[s0 * 64 + lane] + y[s1 * 64 + lane]
                 + y[s2 * 64 + lane] + y[s3 * 64 + lane];
        }
        for (; j < dg; j++) acc += y[csr_l[start + j] * 64 + lane];

        float v = acc * invdeg[nodebase + node] + bias[lane]
                + A[(size_t)(nodebase + node) * 128 + 64 + lane];
        v = fmaxf(v, 0.f);
        if (resid) v += resid[(size_t)(nodebase + node) * 64 + lane];
        Xout[(size_t)(nodebase + node) * 64 + lane] = v;
    }
}

// ---------------- per-graph score + top-k + pool + classifier ----------------
__global__ __launch_bounds__(256) void score_pool(
    const float* __restrict__ X3,
    const int* __restrict__ esrc, const int* __restrict__ edst,
    const float* __restrict__ Wpr, const float* __restrict__ bpr,
    const float* __restrict__ Wpo,
    const float* __restrict__ Wlin, const float* __restrict__ blin,
    float* __restrict__ out)
{
    __shared__ float t0[NPG], s[NPG], w[NPG];
    __shared__ float wpr[64], wpo[64];
    __shared__ float pp[4 * 64];
    __shared__ float pooled[64];
    __shared__ float lg[2];
    const int g = blockIdx.x, tid = threadIdx.x;
    if (tid < 64) { wpr[tid] = Wpr[tid]; wpo[tid] = Wpo[tid]; }
    __syncthreads();

    const int nodebase = g * NPG;
    for (int i = tid; i < NPG; i += 256) {
        const float* xr = &X3[(size_t)(nodebase + i) * 64];
        float a0 = 0.f, a1 = 0.f;
        for (int d = 0; d < 64; d++) { float x = xr[d]; a0 += x * wpr[d]; a1 += x * wpo[d]; }
        t0[i] = a0;
        s[i] = bpr[0] + a1;
    }
    __syncthreads();
    const int ebase = g * EPG;
    for (int e = tid; e < EPG; e += 256) {
        int ls = esrc[ebase + e] - nodebase;
        int ld = edst[ebase + e] - nodebase;
        atomicAdd(&s[ld], t0[ls]);
    }
    __syncthreads();
    for (int i = tid; i < NPG; i += 256) {
        float si = s[i];
        int cnt = 0;
        for (int j = 0; j < NPG; j++) {
            float sj = s[j];
            cnt += (sj > si) || (sj == si && j < i);
        }
        w[i] = (cnt < KSEL) ? tanhf(si) * (1.f / KSEL) : 0.f;
    }
    __syncthreads();
    const int d = tid & 63, part = tid >> 6;
    float acc = 0.f;
    for (int i = part * 100; i < part * 100 + 100; i++)
        acc += w[i] * X3[(size_t)(nodebase + i) * 64 + d];
    pp[part * 64 + d] = acc;
    __syncthreads();
    if (tid < 64) pooled[tid] = pp[tid] + pp[64 + tid] + pp[128 + tid] + pp[192 + tid];
    __syncthreads();
    if (tid < 2) {
        float l = blin[tid];
        for (int dd = 0; dd < 64; dd++) l += pooled[dd] * Wlin[dd * 2 + tid];
        lg[tid] = l;
    }
    __syncthreads();
    if (tid < 2) {
        float m = fmaxf(lg[0], lg[1]);
        float lse = m + logf(expf(lg[0] - m) + expf(lg[1] - m));
        out[g * 2 + tid] = lg[tid] - lse;
    }
}

extern "C" void kernel_launch(void* const* d_in, const int* in_sizes, int n_in,
                              void* d_out, int out_size, void* d_ws, size_t ws_size,
                              hipStream_t stream) {
    const float* x    = (const float*)d_in[0];
    const int*   eidx = (const int*)d_in[1];
    const float* W1l  = (const float*)d_in[3];
    const float* W1r  = (const float*)d_in[4];
    const float* b1   = (const float*)d_in[5];
    const float* W2l  = (const float*)d_in[6];
    const float* W2r  = (const float*)d_in[7];
    const float* b2   = (const float*)d_in[8];
    const float* W3l  = (const float*)d_in[9];
    const float* W3r  = (const float*)d_in[10];
    const float* b3   = (const float*)d_in[11];
    const float* Wpr  = (const float*)d_in[12];
    const float* bpr  = (const float*)d_in[13];
    const float* Wpo  = (const float*)d_in[14];
    const float* Wlin = (const float*)d_in[15];
    const float* blin = (const float*)d_in[16];

    const int N = in_sizes[0] / F_IN;       // 204800
    const int E = in_sizes[1] / 2;          // 3276800
    const int B = N / NPG;                  // 512
    const int* esrc = eidx;
    const int* edst = eidx + E;

    float* ws = (float*)d_ws;
    float* A      = ws;                                  // [N,128] yz buffer
    float* P0     = A + (size_t)N * 128;                 // [N,64] compact acts
    float* P1     = P0 + (size_t)N * 64;                 // [N,64] compact acts
    float* invdeg = P1 + (size_t)N * 64;                 // [N]
    short* WF1    = (short*)(invdeg + N);                // 7*8*2*512 = 57344 sh
    short* WF2    = WF1 + 57344;                         // 2*8*2*512 = 16384 sh
    short* WF3    = WF2 + 16384;
    int*   csr    = (int*)(WF3 + 16384);                 // [E] local src by dst
    int*   rowptr = csr + E;                             // [N] local offsets
    int*   degs   = rowptr + N;                          // [N]

    pack_wf<<<(7 * 4096 + 255) / 256, 256, 0, stream>>>(W1l, W1r, WF1, 200, 7);
    pack_wf<<<(2 * 4096 + 255) / 256, 256, 0, stream>>>(W2l, W2r, WF2, 64, 2);
    pack_wf<<<(2 * 4096 + 255) / 256, 256, 0, stream>>>(W3l, W3r, WF3, 64, 2);

    // CSR once (shared by all 3 layers)
    csr_build<<<B, 256, 0, stream>>>(esrc, edst, csr, rowptr, degs, invdeg);

    // layer 1: yz = x @ [W1l|W1r]; x1 -> P0
    gemm_mfma<200, 200, 7><<<N / 128, 256, 0, stream>>>(x, WF1, A);
    agg_lds<<<B, 1024, 0, stream>>>(A, csr, rowptr, degs, invdeg, b1, nullptr, P0);

    // layer 2: yz = x1 @ [W2l|W2r]; x2 = relu(...)+x1 -> P1
    gemm_mfma<64, 64, 2><<<N / 128, 256, 0, stream>>>(P0, WF2, A);
    agg_lds<<<B, 1024, 0, stream>>>(A, csr, rowptr, degs, invdeg, b2, P0, P1);

    // layer 3: yz = x2 @ [W3l|W3r]; x3 = relu(...)+x2 -> P0 (x1 dead)
    gemm_mfma<64, 64, 2><<<N / 128, 256, 0, stream>>>(P1, WF3, A);
    agg_lds<<<B, 1024, 0, stream>>>(A, csr, rowptr, degs, invdeg, b3, P1, P0);

    // score + top-k + pool + classifier
    score_pool<<<B, 256, 0, stream>>>(P0, esrc, edst, Wpr, bpr, Wpo, Wlin, blin,
                                      (float*)d_out);
}